// Round 5
// baseline (441.821 us; speedup 1.0000x reference)
//
#include <hip/hip_runtime.h>
#include <stdint.h>

#define B_ 4
#define N_ 2048
#define M_ 2048
#define C_ 1024
#define H_ 16
#define D_ 64
#define SC_ (B_*N_*C_)
#define CC_ (C_*C_)

typedef unsigned short u16;
typedef __attribute__((ext_vector_type(8))) short short8;
typedef __attribute__((ext_vector_type(4))) float f32x4;

#if __has_builtin(__builtin_amdgcn_exp2f)
#define EXP2F __builtin_amdgcn_exp2f
#else
#define EXP2F exp2f
#endif

__device__ inline u16 f2bf(float f) {
    union { float f; uint32_t u; } v; v.f = f;
    uint32_t r = v.u + 0x7fffu + ((v.u >> 16) & 1u);
    return (u16)(r >> 16);
}

// ---------------- pass 1: fp32 -> bf16 conversion of all GEMM inputs ----------
__global__ __launch_bounds__(256) void convert_kernel(
    const float* __restrict__ q, const float* __restrict__ k, const float* __restrict__ v,
    const float* __restrict__ wq, const float* __restrict__ wk,
    const float* __restrict__ wv, const float* __restrict__ wp,
    u16* __restrict__ qf, u16* __restrict__ kf, u16* __restrict__ vf,
    u16* __restrict__ wqb, u16* __restrict__ wkb, u16* __restrict__ wvb, u16* __restrict__ wpb)
{
    const int SC4 = SC_ / 4;
    const int CC4 = CC_ / 4;
    const int total = 3 * SC4 + 4 * CC4;
    for (int i = blockIdx.x * 256 + threadIdx.x; i < total; i += gridDim.x * 256) {
        const float* src; u16* dst; int off;
        if (i < 3 * SC4) {
            int seg = i >> 21;
            off = (i & (SC4 - 1)) << 2;
            src = seg == 0 ? q : seg == 1 ? k : v;
            dst = seg == 0 ? qf : seg == 1 ? kf : vf;
        } else {
            int j = i - 3 * SC4;
            int seg = j >> 18;
            off = (j & (CC4 - 1)) << 2;
            src = seg == 0 ? wq : seg == 1 ? wk : seg == 2 ? wv : wp;
            dst = seg == 0 ? wqb : seg == 1 ? wkb : seg == 2 ? wvb : wpb;
        }
        float4 val = *(const float4*)(src + off);
        ushort4 h;
        h.x = f2bf(val.x); h.y = f2bf(val.y); h.z = f2bf(val.z); h.w = f2bf(val.w);
        *(ushort4*)(dst + off) = h;
    }
}

// ---------------- bf16 GEMM, double-buffered single-barrier K-loop ------------
// C[m][n] = scale * sum_k A[m][k] W[n][k]. 1D grid 512: m-tile = f&63 (XCD-sharing),
// n-tile = f>>6, so all n-tiles of one A-tile land on one XCD -> A rows L2-resident.
template<int OMODE>
__global__ __launch_bounds__(256) void gemm_lds(
    const u16* __restrict__ A, const u16* __restrict__ Wb,
    const float* __restrict__ bias, void* __restrict__ Op, float scale)
{
    const int K = 1024;
    __shared__ u16 SH[2 * 8192];   // [buf][As 4096 u16 | Bs 4096 u16] = 32 KB
    const int tid = threadIdx.x;
    const int wid = tid >> 6, lane = tid & 63;
    const int quad = lane >> 4, l15 = lane & 15;
    const int f = blockIdx.x;
    const int m0 = (f & 63) * 128, n0 = (f >> 6) * 128;
    const int wm = (wid >> 1) * 64, wn = (wid & 1) * 64;

    // per-thread staging offsets (2 slots each for A and B)
    size_t aoff[2], boff[2];
    int dsto[2];
#pragma unroll
    for (int i = 0; i < 2; ++i) {
        int s = tid + i * 256;
        int row = s >> 2, c8 = (s & 3) << 3;
        aoff[i] = (size_t)(m0 + row) * K + c8;
        boff[i] = (size_t)(n0 + row) * K + c8;
        dsto[i] = s * 8;
    }

    f32x4 acc[4][4];
#pragma unroll
    for (int i = 0; i < 4; ++i)
#pragma unroll
        for (int j = 0; j < 4; ++j) acc[i][j] = f32x4{0.f, 0.f, 0.f, 0.f};

    // prologue: tile k0=0 -> buf 0
#pragma unroll
    for (int i = 0; i < 2; ++i) {
        __builtin_amdgcn_global_load_lds(
            (const __attribute__((address_space(1))) void*)(A + aoff[i]),
            (__attribute__((address_space(3))) void*)(SH + dsto[i]), 16, 0, 0);
        __builtin_amdgcn_global_load_lds(
            (const __attribute__((address_space(1))) void*)(Wb + boff[i]),
            (__attribute__((address_space(3))) void*)(SH + 4096 + dsto[i]), 16, 0, 0);
    }

    for (int it = 0; it < 32; ++it) {
        const int cur = (it & 1) * 8192;
        __syncthreads();   // compiler drains vmcnt here == wait for tile `it`
        if (it + 1 < 32) {
            const int nxt = ((it + 1) & 1) * 8192;
            const int k0n = (it + 1) * 32;
#pragma unroll
            for (int i = 0; i < 2; ++i) {
                __builtin_amdgcn_global_load_lds(
                    (const __attribute__((address_space(1))) void*)(A + aoff[i] + k0n),
                    (__attribute__((address_space(3))) void*)(SH + nxt + dsto[i]), 16, 0, 0);
                __builtin_amdgcn_global_load_lds(
                    (const __attribute__((address_space(1))) void*)(Wb + boff[i] + k0n),
                    (__attribute__((address_space(3))) void*)(SH + nxt + 4096 + dsto[i]), 16, 0, 0);
            }
        }
        short8 av[4], bv[4];
#pragma unroll
        for (int i = 0; i < 4; ++i)
            av[i] = *(const short8*)(SH + cur + (wm + i * 16 + l15) * 32 + quad * 8);
#pragma unroll
        for (int j = 0; j < 4; ++j)
            bv[j] = *(const short8*)(SH + cur + 4096 + (wn + j * 16 + l15) * 32 + quad * 8);
#pragma unroll
        for (int i = 0; i < 4; ++i)
#pragma unroll
            for (int j = 0; j < 4; ++j)
                acc[i][j] = __builtin_amdgcn_mfma_f32_16x16x32_bf16(av[i], bv[j], acc[i][j], 0, 0, 0);
    }

    if (OMODE == 2) {
#pragma unroll
        for (int j = 0; j < 4; ++j) {
            int col = n0 + wn + j * 16 + l15;
            float bb = bias[col];
#pragma unroll
            for (int i = 0; i < 4; ++i) {
                int row = m0 + wm + i * 16 + quad * 4;
#pragma unroll
                for (int r = 0; r < 4; ++r)
                    ((float*)Op)[(size_t)(row + r) * 1024 + col] = acc[i][j][r] * scale + bb;
            }
        }
    } else if (OMODE == 0) {
#pragma unroll
        for (int j = 0; j < 4; ++j) {
            int col = n0 + wn + j * 16 + l15;
#pragma unroll
            for (int i = 0; i < 4; ++i) {
                int row = m0 + wm + i * 16 + quad * 4;
#pragma unroll
                for (int r = 0; r < 4; ++r)
                    ((u16*)Op)[(size_t)(row + r) * 1024 + col] = f2bf(acc[i][j][r] * scale);
            }
        }
    } else {  // OMODE == 1: vT[((b*16+h)*64+d)][m]
#pragma unroll
        for (int j = 0; j < 4; ++j) {
            int col = n0 + wn + j * 16 + l15;
            int hh = col >> 6, dd = col & 63;
#pragma unroll
            for (int i = 0; i < 4; ++i) {
                int row = m0 + wm + i * 16 + quad * 4;
                int bb = row >> 11, mm = row & 2047;
                ushort4 hv;
                hv.x = f2bf(acc[i][j][0] * scale);
                hv.y = f2bf(acc[i][j][1] * scale);
                hv.z = f2bf(acc[i][j][2] * scale);
                hv.w = f2bf(acc[i][j][3] * scale);
                *(ushort4*)((u16*)Op + (((size_t)bb * 16 + hh) * 64 + dd) * 2048 + mm) = hv;
            }
        }
    }
}

// ---------------- flash attention: split-key waves, dbuf, XCD-swizzled -------
// 1D grid 2048: bh = f&63 (all 32 q-tiles of one (b,h) share an XCD -> K/V L2-
// resident: 8 bh per XCD * 512 KB = 4 MB = L2), qt = f>>6.
// Single barrier per kv-iter; prefetch issued after barrier overlaps compute.
__global__ __launch_bounds__(256, 4) void attn_kernel(
    const u16* __restrict__ qg, const u16* __restrict__ kg,
    const u16* __restrict__ vT, u16* __restrict__ xb)
{
    __shared__ __align__(16) char smem[32768 + 4096];
    u16* KV = (u16*)smem;           // [buf 2][Ks 4096 u16 | Vs 4096 u16]
    float* Ored = (float*)smem;     // epilogue alias (16 KB, buf0 region)
    float* Lred = (float*)(smem + 32768);

    const int tid = threadIdx.x;
    const int wid = tid >> 6, lane = tid & 63;
    const int quad = lane >> 4, l15 = lane & 15;
    const int f = blockIdx.x;
    const int bh = f & 63, qt = f >> 6;
    const int b = bh >> 4, h = bh & 15;

    // ---- Q fragments, loop-invariant, direct from global
    const u16* qbase = qg + ((size_t)(b * N_ + qt * 64)) * C_ + h * 64;
    short8 qf[4][2];
#pragma unroll
    for (int qb2 = 0; qb2 < 4; ++qb2)
#pragma unroll
        for (int ch = 0; ch < 2; ++ch)
            qf[qb2][ch] = *(const short8*)(qbase + (size_t)(qb2 * 16 + l15) * C_ + ch * 32 + quad * 8);

    // ---- staging pointers (XOR-swizzled global group; LDS dest lane-linear)
    const u16* kptr[2];
    const u16* vptr[2];
    int dsto[2];
#pragma unroll
    for (int i = 0; i < 2; ++i) {
        int s = tid + i * 256;
        int row = s >> 3, g = s & 7;
        int gsw = g ^ (row & 7);
        kptr[i] = kg + ((size_t)(b * M_ + row)) * C_ + h * 64 + gsw * 8;
        vptr[i] = vT + (((size_t)b * 16 + h) * 64 + row) * M_ + gsw * 8;
        dsto[i] = s * 8;
    }

    f32x4 acc_o[4][4];  // [qb][db]: O^T[d=db*16+quad*4+reg][qrow=qb*16+l15]
#pragma unroll
    for (int i = 0; i < 4; ++i)
#pragma unroll
        for (int j = 0; j < 4; ++j) acc_o[i][j] = f32x4{0.f, 0.f, 0.f, 0.f};
    float lsum[4] = {0.f, 0.f, 0.f, 0.f};

    // frag read offsets within a buffer
    const int rk = wid * 16 + l15, swk = rk & 7;
    const int kfo0 = rk * 64 + ((0 * 4 + quad) ^ swk) * 8;
    const int kfo1 = rk * 64 + ((1 * 4 + quad) ^ swk) * 8;
    int vfo[4];
#pragma unroll
    for (int db = 0; db < 4; ++db) {
        int rv = db * 16 + l15, swv = rv & 7;
        vfo[db] = 4096 + rv * 64 + (((wid * 2 + (quad >> 1)) ^ swv) << 3) + ((quad & 1) << 2);
    }

    // persistent zero-high fragments
    union { short8 s; uint32_t u[4]; } pfrag[4], vfu;
#pragma unroll
    for (int qb2 = 0; qb2 < 4; ++qb2) { pfrag[qb2].u[2] = 0; pfrag[qb2].u[3] = 0; }
    vfu.u[2] = 0; vfu.u[3] = 0;

    // prologue: tile 0 -> buf 0
#pragma unroll
    for (int i = 0; i < 2; ++i) {
        __builtin_amdgcn_global_load_lds(
            (const __attribute__((address_space(1))) void*)(kptr[i]),
            (__attribute__((address_space(3))) void*)(KV + dsto[i]), 16, 0, 0);
        __builtin_amdgcn_global_load_lds(
            (const __attribute__((address_space(1))) void*)(vptr[i]),
            (__attribute__((address_space(3))) void*)(KV + 4096 + dsto[i]), 16, 0, 0);
    }

    for (int it = 0; it < 32; ++it) {
        const int cur = (it & 1) * 8192;
        __syncthreads();   // drain == wait for tile `it`; syncs all waves' stores
        if (it + 1 < 32) {
            const int nxt = ((it + 1) & 1) * 8192;
            const int kvn = (it + 1) * 64;
#pragma unroll
            for (int i = 0; i < 2; ++i) {
                __builtin_amdgcn_global_load_lds(
                    (const __attribute__((address_space(1))) void*)(kptr[i] + (size_t)kvn * C_),
                    (__attribute__((address_space(3))) void*)(KV + nxt + dsto[i]), 16, 0, 0);
                __builtin_amdgcn_global_load_lds(
                    (const __attribute__((address_space(1))) void*)(vptr[i] + kvn),
                    (__attribute__((address_space(3))) void*)(KV + nxt + 4096 + dsto[i]), 16, 0, 0);
            }
        }

        // ---- S^T = K*Q^T
        short8 kf0 = *(const short8*)(KV + cur + kfo0);
        short8 kf1 = *(const short8*)(KV + cur + kfo1);
        f32x4 sc[4];
#pragma unroll
        for (int qb2 = 0; qb2 < 4; ++qb2) {
            sc[qb2] = f32x4{0.f, 0.f, 0.f, 0.f};
            sc[qb2] = __builtin_amdgcn_mfma_f32_16x16x32_bf16(kf0, qf[qb2][0], sc[qb2], 0, 0, 0);
            sc[qb2] = __builtin_amdgcn_mfma_f32_16x16x32_bf16(kf1, qf[qb2][1], sc[qb2], 0, 0, 0);
        }

        // ---- p = exp2(s), truncate-pack to bf16 pairs
#pragma unroll
        for (int qb2 = 0; qb2 < 4; ++qb2) {
            float e0 = EXP2F(sc[qb2][0]);
            float e1 = EXP2F(sc[qb2][1]);
            float e2 = EXP2F(sc[qb2][2]);
            float e3 = EXP2F(sc[qb2][3]);
            lsum[qb2] += (e0 + e1) + (e2 + e3);
            pfrag[qb2].u[0] = __builtin_amdgcn_perm(__builtin_bit_cast(uint32_t, e1),
                                                    __builtin_bit_cast(uint32_t, e0), 0x07060302u);
            pfrag[qb2].u[1] = __builtin_amdgcn_perm(__builtin_bit_cast(uint32_t, e3),
                                                    __builtin_bit_cast(uint32_t, e2), 0x07060302u);
        }

        // ---- O^T += V^T * P^T
#pragma unroll
        for (int db = 0; db < 4; ++db) {
            uint2 vlo = *(const uint2*)(KV + cur + vfo[db]);
            vfu.u[0] = vlo.x; vfu.u[1] = vlo.y;
#pragma unroll
            for (int qb2 = 0; qb2 < 4; ++qb2)
                acc_o[qb2][db] = __builtin_amdgcn_mfma_f32_16x16x32_bf16(vfu.s, pfrag[qb2].s, acc_o[qb2][db], 0, 0, 0);
        }
    }

    // ---- denominator
    __syncthreads();
    *(f32x4*)(Lred + (((wid * 4 + quad) * 16 + l15) << 2)) =
        f32x4{lsum[0], lsum[1], lsum[2], lsum[3]};
    __syncthreads();
    float dsum = 0.f;
#pragma unroll
    for (int q2 = 0; q2 < 4; ++q2)
        dsum += Lred[(((quad * 4 + q2) * 16 + l15) << 2) + wid];
    dsum += __shfl_xor(dsum, 16);
    dsum += __shfl_xor(dsum, 32);
    float dinv = 1.f / dsum;

    // ---- cross-wave O reduction (Ored aliases buf0)
#pragma unroll
    for (int qb2 = 0; qb2 < 4; ++qb2) {
        __syncthreads();
#pragma unroll
        for (int db = 0; db < 4; ++db)
            *(f32x4*)(Ored + (((wid * 4 + db) * 64 + lane) << 2)) = acc_o[qb2][db];
        __syncthreads();
        if (wid == qb2) {
#pragma unroll
            for (int w2 = 0; w2 < 4; ++w2) {
                if (w2 == wid) continue;
#pragma unroll
                for (int db = 0; db < 4; ++db) {
                    f32x4 t = *(const f32x4*)(Ored + (((w2 * 4 + db) * 64 + lane) << 2));
                    acc_o[qb2][db] += t;
                }
            }
            size_t ob = ((size_t)(b * N_ + qt * 64 + wid * 16 + l15)) * C_ + h * 64;
#pragma unroll
            for (int db = 0; db < 4; ++db) {
                ushort4 st;
                st.x = f2bf(acc_o[qb2][db][0] * dinv);
                st.y = f2bf(acc_o[qb2][db][1] * dinv);
                st.z = f2bf(acc_o[qb2][db][2] * dinv);
                st.w = f2bf(acc_o[qb2][db][3] * dinv);
                *(ushort4*)(xb + ob + db * 16 + quad * 4) = st;
            }
        }
    }
}

extern "C" void kernel_launch(void* const* d_in, const int* in_sizes, int n_in,
                              void* d_out, int out_size, void* d_ws, size_t ws_size,
                              hipStream_t stream) {
    const float* query = (const float*)d_in[0];
    const float* key   = (const float*)d_in[1];
    const float* value = (const float*)d_in[2];
    const float* Wq    = (const float*)d_in[3];
    const float* Wk    = (const float*)d_in[4];
    const float* Wv    = (const float*)d_in[5];
    const float* Wpm   = (const float*)d_in[6];
    const float* bp    = (const float*)d_in[7];
    float* out = (float*)d_out;

    u16* base = (u16*)d_ws;
    u16* qf  = base;
    u16* kf  = base + (size_t)SC_;
    u16* vf  = base + (size_t)2 * SC_;
    u16* kb  = base + (size_t)3 * SC_;
    u16* Wqb = base + (size_t)4 * SC_;
    u16* Wkb = Wqb + CC_;
    u16* Wvb = Wkb + CC_;
    u16* Wpb = Wvb + CC_;
    u16* vTp = kf;   // alias (kf dead after k-GEMM)
    u16* qb  = vf;   // alias (vf dead after v-GEMM)
    u16* xb  = qf;   // alias (qf dead after q-GEMM)

    hipLaunchKernelGGL(convert_kernel, dim3(4096), dim3(256), 0, stream,
                       query, key, value, Wq, Wk, Wv, Wpm,
                       qf, kf, vf, Wqb, Wkb, Wvb, Wpb);

    dim3 gg(512), bb(256);
    hipLaunchKernelGGL((gemm_lds<0>), gg, bb, 0, stream, kf, Wkb, nullptr, (void*)kb, 1.0f);
    hipLaunchKernelGGL((gemm_lds<1>), gg, bb, 0, stream, vf, Wvb, nullptr, (void*)vTp, 1.0f);
    hipLaunchKernelGGL((gemm_lds<0>), gg, bb, 0, stream, qf, Wqb, nullptr, (void*)qb,
                       0.125f * 1.44269504088896340736f);

    hipLaunchKernelGGL(attn_kernel, dim3(2048), bb, 0, stream, qb, kb, vTp, xb);

    hipLaunchKernelGGL((gemm_lds<2>), gg, bb, 0, stream, xb, Wpb, bp, (void*)out, 1.0f);
}

// Round 6
// 370.003 us; speedup vs baseline: 1.1941x; 1.1941x over previous
//
#include <hip/hip_runtime.h>
#include <stdint.h>

#define B_ 4
#define N_ 2048
#define M_ 2048
#define C_ 1024
#define H_ 16
#define D_ 64
#define SC_ (B_*N_*C_)
#define CC_ (C_*C_)

typedef unsigned short u16;
typedef __attribute__((ext_vector_type(8))) short short8;
typedef __attribute__((ext_vector_type(4))) float f32x4;

#if __has_builtin(__builtin_amdgcn_exp2f)
#define EXP2F __builtin_amdgcn_exp2f
#else
#define EXP2F exp2f
#endif

__device__ inline u16 f2bf(float f) {
    union { float f; uint32_t u; } v; v.f = f;
    uint32_t r = v.u + 0x7fffu + ((v.u >> 16) & 1u);
    return (u16)(r >> 16);
}

// ---------------- pass 1: fp32 -> bf16 conversion of all GEMM inputs ----------
__global__ __launch_bounds__(256) void convert_kernel(
    const float* __restrict__ q, const float* __restrict__ k, const float* __restrict__ v,
    const float* __restrict__ wq, const float* __restrict__ wk,
    const float* __restrict__ wv, const float* __restrict__ wp,
    u16* __restrict__ qf, u16* __restrict__ kf, u16* __restrict__ vf,
    u16* __restrict__ wqb, u16* __restrict__ wkb, u16* __restrict__ wvb, u16* __restrict__ wpb)
{
    const int SC4 = SC_ / 4;
    const int CC4 = CC_ / 4;
    const int total = 3 * SC4 + 4 * CC4;
    for (int i = blockIdx.x * 256 + threadIdx.x; i < total; i += gridDim.x * 256) {
        const float* src; u16* dst; int off;
        if (i < 3 * SC4) {
            int seg = i >> 21;
            off = (i & (SC4 - 1)) << 2;
            src = seg == 0 ? q : seg == 1 ? k : v;
            dst = seg == 0 ? qf : seg == 1 ? kf : vf;
        } else {
            int j = i - 3 * SC4;
            int seg = j >> 18;
            off = (j & (CC4 - 1)) << 2;
            src = seg == 0 ? wq : seg == 1 ? wk : seg == 2 ? wv : wp;
            dst = seg == 0 ? wqb : seg == 1 ? wkb : seg == 2 ? wvb : wpb;
        }
        float4 val = *(const float4*)(src + off);
        ushort4 h;
        h.x = f2bf(val.x); h.y = f2bf(val.y); h.z = f2bf(val.z); h.w = f2bf(val.w);
        *(ushort4*)(dst + off) = h;
    }
}

// ---------------- bf16 GEMM, double-buffered single-barrier K-loop ------------
// C[m][n] = scale * sum_k A[m][k] W[n][k]. 1D grid 512: m-tile = f&63 (XCD-sharing),
// n-tile = f>>6, so all n-tiles of one A-tile land on one XCD -> A rows L2-resident.
template<int OMODE>
__global__ __launch_bounds__(256) void gemm_lds(
    const u16* __restrict__ A, const u16* __restrict__ Wb,
    const float* __restrict__ bias, void* __restrict__ Op, float scale)
{
    const int K = 1024;
    __shared__ u16 SH[2 * 8192];   // [buf][As 4096 u16 | Bs 4096 u16] = 32 KB
    const int tid = threadIdx.x;
    const int wid = tid >> 6, lane = tid & 63;
    const int quad = lane >> 4, l15 = lane & 15;
    const int f = blockIdx.x;
    const int m0 = (f & 63) * 128, n0 = (f >> 6) * 128;
    const int wm = (wid >> 1) * 64, wn = (wid & 1) * 64;

    size_t aoff[2], boff[2];
    int dsto[2];
#pragma unroll
    for (int i = 0; i < 2; ++i) {
        int s = tid + i * 256;
        int row = s >> 2, c8 = (s & 3) << 3;
        aoff[i] = (size_t)(m0 + row) * K + c8;
        boff[i] = (size_t)(n0 + row) * K + c8;
        dsto[i] = s * 8;
    }

    f32x4 acc[4][4];
#pragma unroll
    for (int i = 0; i < 4; ++i)
#pragma unroll
        for (int j = 0; j < 4; ++j) acc[i][j] = f32x4{0.f, 0.f, 0.f, 0.f};

#pragma unroll
    for (int i = 0; i < 2; ++i) {
        __builtin_amdgcn_global_load_lds(
            (const __attribute__((address_space(1))) void*)(A + aoff[i]),
            (__attribute__((address_space(3))) void*)(SH + dsto[i]), 16, 0, 0);
        __builtin_amdgcn_global_load_lds(
            (const __attribute__((address_space(1))) void*)(Wb + boff[i]),
            (__attribute__((address_space(3))) void*)(SH + 4096 + dsto[i]), 16, 0, 0);
    }

    for (int it = 0; it < 32; ++it) {
        const int cur = (it & 1) * 8192;
        __syncthreads();   // drain == wait for tile `it`
        if (it + 1 < 32) {
            const int nxt = ((it + 1) & 1) * 8192;
            const int k0n = (it + 1) * 32;
#pragma unroll
            for (int i = 0; i < 2; ++i) {
                __builtin_amdgcn_global_load_lds(
                    (const __attribute__((address_space(1))) void*)(A + aoff[i] + k0n),
                    (__attribute__((address_space(3))) void*)(SH + nxt + dsto[i]), 16, 0, 0);
                __builtin_amdgcn_global_load_lds(
                    (const __attribute__((address_space(1))) void*)(Wb + boff[i] + k0n),
                    (__attribute__((address_space(3))) void*)(SH + nxt + 4096 + dsto[i]), 16, 0, 0);
            }
        }
        short8 av[4], bv[4];
#pragma unroll
        for (int i = 0; i < 4; ++i)
            av[i] = *(const short8*)(SH + cur + (wm + i * 16 + l15) * 32 + quad * 8);
#pragma unroll
        for (int j = 0; j < 4; ++j)
            bv[j] = *(const short8*)(SH + cur + 4096 + (wn + j * 16 + l15) * 32 + quad * 8);
#pragma unroll
        for (int i = 0; i < 4; ++i)
#pragma unroll
            for (int j = 0; j < 4; ++j)
                acc[i][j] = __builtin_amdgcn_mfma_f32_16x16x32_bf16(av[i], bv[j], acc[i][j], 0, 0, 0);
    }

    if (OMODE == 2) {
#pragma unroll
        for (int j = 0; j < 4; ++j) {
            int col = n0 + wn + j * 16 + l15;
            float bb = bias[col];
#pragma unroll
            for (int i = 0; i < 4; ++i) {
                int row = m0 + wm + i * 16 + quad * 4;
#pragma unroll
                for (int r = 0; r < 4; ++r)
                    ((float*)Op)[(size_t)(row + r) * 1024 + col] = acc[i][j][r] * scale + bb;
            }
        }
    } else if (OMODE == 0) {
#pragma unroll
        for (int j = 0; j < 4; ++j) {
            int col = n0 + wn + j * 16 + l15;
#pragma unroll
            for (int i = 0; i < 4; ++i) {
                int row = m0 + wm + i * 16 + quad * 4;
#pragma unroll
                for (int r = 0; r < 4; ++r)
                    ((u16*)Op)[(size_t)(row + r) * 1024 + col] = f2bf(acc[i][j][r] * scale);
            }
        }
    } else {  // OMODE == 1: vT[((b*16+h)*64+d)][m]
#pragma unroll
        for (int j = 0; j < 4; ++j) {
            int col = n0 + wn + j * 16 + l15;
            int hh = col >> 6, dd = col & 63;
#pragma unroll
            for (int i = 0; i < 4; ++i) {
                int row = m0 + wm + i * 16 + quad * 4;
                int bb = row >> 11, mm = row & 2047;
                ushort4 hv;
                hv.x = f2bf(acc[i][j][0] * scale);
                hv.y = f2bf(acc[i][j][1] * scale);
                hv.z = f2bf(acc[i][j][2] * scale);
                hv.w = f2bf(acc[i][j][3] * scale);
                *(ushort4*)((u16*)Op + (((size_t)bb * 16 + hh) * 64 + dd) * 2048 + mm) = hv;
            }
        }
    }
}

// ---------------- flash attention: split-key waves, dbuf, XCD-swizzled -------
// 1D grid 2048: bh = f&63 (q-tiles of one (b,h) share an XCD; K/V L2-resident),
// qt = f>>6. Single barrier per kv-iter; prefetch overlaps compute.
// launch_bounds (256,3): 84-110 VGPR, no spill (R5's (256,4) spilled -> 3x WRITE_SIZE).
__global__ __launch_bounds__(256, 3) void attn_kernel(
    const u16* __restrict__ qg, const u16* __restrict__ kg,
    const u16* __restrict__ vT, u16* __restrict__ xb)
{
    __shared__ __align__(16) char smem[32768];
    u16* KV = (u16*)smem;           // [buf 2][Ks 4096 u16 | Vs 4096 u16]
    float* Ored = (float*)smem;     // epilogue alias (16 KB, buf0)
    float* Lred = (float*)(smem + 16384);  // epilogue alias (4 KB, buf1 head)

    const int tid = threadIdx.x;
    const int wid = tid >> 6, lane = tid & 63;
    const int quad = lane >> 4, l15 = lane & 15;
    const int f = blockIdx.x;
    const int bh = f & 63, qt = f >> 6;
    const int b = bh >> 4, h = bh & 15;

    // ---- Q fragments, loop-invariant, direct from global
    const u16* qbase = qg + ((size_t)(b * N_ + qt * 64)) * C_ + h * 64;
    short8 qf[4][2];
#pragma unroll
    for (int qb2 = 0; qb2 < 4; ++qb2)
#pragma unroll
        for (int ch = 0; ch < 2; ++ch)
            qf[qb2][ch] = *(const short8*)(qbase + (size_t)(qb2 * 16 + l15) * C_ + ch * 32 + quad * 8);

    // ---- staging pointers (XOR-swizzled global group; LDS dest lane-linear)
    const u16* kptr[2];
    const u16* vptr[2];
    int dsto[2];
#pragma unroll
    for (int i = 0; i < 2; ++i) {
        int s = tid + i * 256;
        int row = s >> 3, g = s & 7;
        int gsw = g ^ (row & 7);
        kptr[i] = kg + ((size_t)(b * M_ + row)) * C_ + h * 64 + gsw * 8;
        vptr[i] = vT + (((size_t)b * 16 + h) * 64 + row) * M_ + gsw * 8;
        dsto[i] = s * 8;
    }

    f32x4 acc_o[4][4];  // [qb][db]: O^T[d=db*16+quad*4+reg][qrow=qb*16+l15]
#pragma unroll
    for (int i = 0; i < 4; ++i)
#pragma unroll
        for (int j = 0; j < 4; ++j) acc_o[i][j] = f32x4{0.f, 0.f, 0.f, 0.f};
    float lsum[4] = {0.f, 0.f, 0.f, 0.f};

    const int rk = wid * 16 + l15, swk = rk & 7;
    const int kfo0 = rk * 64 + ((0 * 4 + quad) ^ swk) * 8;
    const int kfo1 = rk * 64 + ((1 * 4 + quad) ^ swk) * 8;
    int vfo[4];
#pragma unroll
    for (int db = 0; db < 4; ++db) {
        int rv = db * 16 + l15, swv = rv & 7;
        vfo[db] = 4096 + rv * 64 + (((wid * 2 + (quad >> 1)) ^ swv) << 3) + ((quad & 1) << 2);
    }

    union { short8 s; uint32_t u[4]; } pfrag[4], vfu;
#pragma unroll
    for (int qb2 = 0; qb2 < 4; ++qb2) { pfrag[qb2].u[2] = 0; pfrag[qb2].u[3] = 0; }
    vfu.u[2] = 0; vfu.u[3] = 0;

    // prologue: tile 0 -> buf 0
#pragma unroll
    for (int i = 0; i < 2; ++i) {
        __builtin_amdgcn_global_load_lds(
            (const __attribute__((address_space(1))) void*)(kptr[i]),
            (__attribute__((address_space(3))) void*)(KV + dsto[i]), 16, 0, 0);
        __builtin_amdgcn_global_load_lds(
            (const __attribute__((address_space(1))) void*)(vptr[i]),
            (__attribute__((address_space(3))) void*)(KV + 4096 + dsto[i]), 16, 0, 0);
    }

    for (int it = 0; it < 32; ++it) {
        const int cur = (it & 1) * 8192;
        __syncthreads();   // drain == wait for tile `it`
        if (it + 1 < 32) {
            const int nxt = ((it + 1) & 1) * 8192;
            const int kvn = (it + 1) * 64;
#pragma unroll
            for (int i = 0; i < 2; ++i) {
                __builtin_amdgcn_global_load_lds(
                    (const __attribute__((address_space(1))) void*)(kptr[i] + (size_t)kvn * C_),
                    (__attribute__((address_space(3))) void*)(KV + nxt + dsto[i]), 16, 0, 0);
                __builtin_amdgcn_global_load_lds(
                    (const __attribute__((address_space(1))) void*)(vptr[i] + kvn),
                    (__attribute__((address_space(3))) void*)(KV + nxt + 4096 + dsto[i]), 16, 0, 0);
            }
        }

        // ---- S^T = K*Q^T
        short8 kf0 = *(const short8*)(KV + cur + kfo0);
        short8 kf1 = *(const short8*)(KV + cur + kfo1);
        f32x4 sc[4];
#pragma unroll
        for (int qb2 = 0; qb2 < 4; ++qb2) {
            sc[qb2] = f32x4{0.f, 0.f, 0.f, 0.f};
            sc[qb2] = __builtin_amdgcn_mfma_f32_16x16x32_bf16(kf0, qf[qb2][0], sc[qb2], 0, 0, 0);
            sc[qb2] = __builtin_amdgcn_mfma_f32_16x16x32_bf16(kf1, qf[qb2][1], sc[qb2], 0, 0, 0);
        }

        // ---- p = exp2(s), truncate-pack to bf16 pairs
#pragma unroll
        for (int qb2 = 0; qb2 < 4; ++qb2) {
            float e0 = EXP2F(sc[qb2][0]);
            float e1 = EXP2F(sc[qb2][1]);
            float e2 = EXP2F(sc[qb2][2]);
            float e3 = EXP2F(sc[qb2][3]);
            lsum[qb2] += (e0 + e1) + (e2 + e3);
            pfrag[qb2].u[0] = __builtin_amdgcn_perm(__builtin_bit_cast(uint32_t, e1),
                                                    __builtin_bit_cast(uint32_t, e0), 0x07060302u);
            pfrag[qb2].u[1] = __builtin_amdgcn_perm(__builtin_bit_cast(uint32_t, e3),
                                                    __builtin_bit_cast(uint32_t, e2), 0x07060302u);
        }

        // ---- O^T += V^T * P^T
#pragma unroll
        for (int db = 0; db < 4; ++db) {
            uint2 vlo = *(const uint2*)(KV + cur + vfo[db]);
            vfu.u[0] = vlo.x; vfu.u[1] = vlo.y;
#pragma unroll
            for (int qb2 = 0; qb2 < 4; ++qb2)
                acc_o[qb2][db] = __builtin_amdgcn_mfma_f32_16x16x32_bf16(vfu.s, pfrag[qb2].s, acc_o[qb2][db], 0, 0, 0);
        }
    }

    // ---- denominator (Lred aliases buf1 head; all buf1 reads are behind the barrier)
    __syncthreads();
    *(f32x4*)(Lred + (((wid * 4 + quad) * 16 + l15) << 2)) =
        f32x4{lsum[0], lsum[1], lsum[2], lsum[3]};
    __syncthreads();
    float dsum = 0.f;
#pragma unroll
    for (int q2 = 0; q2 < 4; ++q2)
        dsum += Lred[(((quad * 4 + q2) * 16 + l15) << 2) + wid];
    dsum += __shfl_xor(dsum, 16);
    dsum += __shfl_xor(dsum, 32);
    float dinv = 1.f / dsum;

    // ---- cross-wave O reduction (Ored aliases buf0)
#pragma unroll
    for (int qb2 = 0; qb2 < 4; ++qb2) {
        __syncthreads();
#pragma unroll
        for (int db = 0; db < 4; ++db)
            *(f32x4*)(Ored + (((wid * 4 + db) * 64 + lane) << 2)) = acc_o[qb2][db];
        __syncthreads();
        if (wid == qb2) {
#pragma unroll
            for (int w2 = 0; w2 < 4; ++w2) {
                if (w2 == wid) continue;
#pragma unroll
                for (int db = 0; db < 4; ++db) {
                    f32x4 t = *(const f32x4*)(Ored + (((w2 * 4 + db) * 64 + lane) << 2));
                    acc_o[qb2][db] += t;
                }
            }
            size_t ob = ((size_t)(b * N_ + qt * 64 + wid * 16 + l15)) * C_ + h * 64;
#pragma unroll
            for (int db = 0; db < 4; ++db) {
                ushort4 st;
                st.x = f2bf(acc_o[qb2][db][0] * dinv);
                st.y = f2bf(acc_o[qb2][db][1] * dinv);
                st.z = f2bf(acc_o[qb2][db][2] * dinv);
                st.w = f2bf(acc_o[qb2][db][3] * dinv);
                *(ushort4*)(xb + ob + db * 16 + quad * 4) = st;
            }
        }
    }
}

extern "C" void kernel_launch(void* const* d_in, const int* in_sizes, int n_in,
                              void* d_out, int out_size, void* d_ws, size_t ws_size,
                              hipStream_t stream) {
    const float* query = (const float*)d_in[0];
    const float* key   = (const float*)d_in[1];
    const float* value = (const float*)d_in[2];
    const float* Wq    = (const float*)d_in[3];
    const float* Wk    = (const float*)d_in[4];
    const float* Wv    = (const float*)d_in[5];
    const float* Wpm   = (const float*)d_in[6];
    const float* bp    = (const float*)d_in[7];
    float* out = (float*)d_out;

    u16* base = (u16*)d_ws;
    u16* qf  = base;
    u16* kf  = base + (size_t)SC_;
    u16* vf  = base + (size_t)2 * SC_;
    u16* kb  = base + (size_t)3 * SC_;
    u16* Wqb = base + (size_t)4 * SC_;
    u16* Wkb = Wqb + CC_;
    u16* Wvb = Wkb + CC_;
    u16* Wpb = Wvb + CC_;
    u16* vTp = kf;   // alias (kf dead after k-GEMM)
    u16* qb  = vf;   // alias (vf dead after v-GEMM)
    u16* xb  = qf;   // alias (qf dead after q-GEMM)

    hipLaunchKernelGGL(convert_kernel, dim3(4096), dim3(256), 0, stream,
                       query, key, value, Wq, Wk, Wv, Wpm,
                       qf, kf, vf, Wqb, Wkb, Wvb, Wpb);

    dim3 gg(512), bb(256);
    hipLaunchKernelGGL((gemm_lds<0>), gg, bb, 0, stream, kf, Wkb, nullptr, (void*)kb, 1.0f);
    hipLaunchKernelGGL((gemm_lds<1>), gg, bb, 0, stream, vf, Wvb, nullptr, (void*)vTp, 1.0f);
    hipLaunchKernelGGL((gemm_lds<0>), gg, bb, 0, stream, qf, Wqb, nullptr, (void*)qb,
                       0.125f * 1.44269504088896340736f);

    hipLaunchKernelGGL(attn_kernel, dim3(2048), bb, 0, stream, qb, kb, vTp, xb);

    hipLaunchKernelGGL((gemm_lds<2>), gg, bb, 0, stream, xb, Wpb, bp, (void*)out, 1.0f);
}